// Round 8
// baseline (1134.425 us; speedup 1.0000x reference)
//
#include <hip/hip_runtime.h>
#include <hip/hip_bf16.h>
#include <math.h>

#define MDIM 2048
#define KDIM 1024
#define BIGF 1e9f
#define NSTRIP 32   // strips per matrix, 64 rows each (1 row per lane)
// KPH=32 steps/phase. Skew D=4 phases (128 steps). Strip s: phases [4s, 4s+65].

typedef unsigned short ushort;
typedef unsigned int uint;
typedef __attribute__((ext_vector_type(8))) short short8v;
typedef __attribute__((ext_vector_type(8))) ushort ushort8v;
typedef __attribute__((ext_vector_type(4))) float f32x4;
typedef __attribute__((ext_vector_type(4), aligned(4))) float f4u;

// ---------------- row normalization: one wave per row, emits bf16 ----------
__device__ __forceinline__ ushort f2bf(float f) {
  uint b = __builtin_bit_cast(uint, f);
  b += 0x7FFFu + ((b >> 16) & 1u);
  return (ushort)(b >> 16);
}

__global__ __launch_bounds__(256) void normalize_rows(
    const float* __restrict__ x, const float* __restrict__ y,
    ushort* __restrict__ xb, ushort* __restrict__ yb) {
  int wave = (blockIdx.x * blockDim.x + threadIdx.x) >> 6;
  int lane = threadIdx.x & 63;
  const float* src;
  ushort* dst;
  int row;
  if (wave < MDIM) { src = x; dst = xb; row = wave; }
  else             { src = y; dst = yb; row = wave - MDIM; }
  const float* r = src + (size_t)row * KDIM;
  ushort* w = dst + (size_t)row * KDIM;
  float ss = 0.f;
  for (int c = lane * 4; c < KDIM; c += 64 * 4) {
    float4 v = *(const float4*)&r[c];
    ss += v.x * v.x + v.y * v.y + v.z * v.z + v.w * v.w;
  }
  #pragma unroll
  for (int off = 32; off; off >>= 1) ss += __shfl_xor(ss, off, 64);
  float inv = 1.f / fmaxf(sqrtf(ss), 1e-12f);
  for (int c = lane * 4; c < KDIM; c += 64 * 4) {
    float4 v = *(const float4*)&r[c];
    uint2 o;
    o.x = (uint)f2bf(v.x * inv) | ((uint)f2bf(v.y * inv) << 16);
    o.y = (uint)f2bf(v.z * inv) | ((uint)f2bf(v.w * inv) << 16);
    *(uint2*)&w[c] = o;
  }
}

// ------------- cost GEMM (bf16 MFMA): C' = (1 - A.B^T) * kexp -------------
__global__ __launch_bounds__(256) void gemm_cost_mfma(
    const ushort* __restrict__ xb, const ushort* __restrict__ yb,
    float* __restrict__ cost_base, const float* __restrict__ gamma_p) {
  int z = blockIdx.z;
  const ushort* A = (z == 2) ? yb : xb;
  const ushort* B = (z == 0) ? yb : ((z == 1) ? xb : yb);
  float* C = cost_base + (size_t)z * MDIM * MDIM;
  float g = fmaxf(fabsf(gamma_p[0]), 1e-4f);
  float kexp = 1.44269504089f / g;

  __shared__ ushort As[128 * 64];
  __shared__ ushort Bs[128 * 64];

  int tid = threadIdx.x;
  int w = tid >> 6, l = tid & 63;
  int wr = w >> 1, wc = w & 1;
  int abase = blockIdx.y * 128;
  int bbase = blockIdx.x * 128;

  f32x4 acc[4][4] = {};

  for (int k0 = 0; k0 < KDIM; k0 += 64) {
    ushort8v va[4], vb[4];
    #pragma unroll
    for (int q = 0; q < 4; ++q) {
      int slot = q * 256 + tid;
      int row = slot >> 3, sc = slot & 7;
      va[q] = *(const ushort8v*)&A[(size_t)(abase + row) * KDIM + k0 + sc * 8];
      vb[q] = *(const ushort8v*)&B[(size_t)(bbase + row) * KDIM + k0 + sc * 8];
    }
    __syncthreads();
    #pragma unroll
    for (int q = 0; q < 4; ++q) {
      int slot = q * 256 + tid;
      int row = slot >> 3, sc = slot & 7;
      int off = row * 64 + ((sc ^ (row & 7)) << 3);
      *(ushort8v*)&As[off] = va[q];
      *(ushort8v*)&Bs[off] = vb[q];
    }
    __syncthreads();
    #pragma unroll
    for (int kk = 0; kk < 2; ++kk) {
      short8v af[4], bf[4];
      #pragma unroll
      for (int m = 0; m < 4; ++m) {
        int row = wr * 64 + m * 16 + (l & 15);
        int kg = kk * 4 + (l >> 4);
        af[m] = *(const short8v*)&As[row * 64 + ((kg ^ (row & 7)) << 3)];
      }
      #pragma unroll
      for (int n = 0; n < 4; ++n) {
        int row = wc * 64 + n * 16 + (l & 15);
        int kg = kk * 4 + (l >> 4);
        bf[n] = *(const short8v*)&Bs[row * 64 + ((kg ^ (row & 7)) << 3)];
      }
      #pragma unroll
      for (int m = 0; m < 4; ++m)
        #pragma unroll
        for (int n = 0; n < 4; ++n)
          acc[m][n] = __builtin_amdgcn_mfma_f32_16x16x32_bf16(
              af[m], bf[n], acc[m][n], 0, 0, 0);
    }
  }
  #pragma unroll
  for (int m = 0; m < 4; ++m) {
    int row0 = abase + wr * 64 + m * 16 + (l >> 4) * 4;
    #pragma unroll
    for (int n = 0; n < 4; ++n) {
      int col = bbase + wc * 64 + n * 16 + (l & 15);
      f32x4 v = acc[m][n];
      #pragma unroll
      for (int r = 0; r < 4; ++r)
        C[(size_t)(row0 + r) * MDIM + col] = (1.0f - v[r]) * kexp;
    }
  }
}

// ---------------- soft-DTW: pinned-register wavefront, KPH=32 ----------------
__device__ __forceinline__ float fexp2(float x) { return __builtin_amdgcn_exp2f(x); }
__device__ __forceinline__ float flog2(float x) { return __builtin_amdgcn_logf(x); }

__device__ __forceinline__ float shr1(float v) {  // lane i <- lane i-1
  int r = __builtin_amdgcn_update_dpp(__builtin_bit_cast(int, v),
                                      __builtin_bit_cast(int, v),
                                      0x138 /*wave_shr:1*/, 0xF, 0xF, false);
  return __builtin_bit_cast(float, r);
}

__device__ __forceinline__ float aload(const float* p) {
  return __hip_atomic_load(p, __ATOMIC_RELAXED, __HIP_MEMORY_SCOPE_AGENT);
}

// force staged window into registers; orders the loads before this point
__device__ __forceinline__ void pin8(f4u (&b)[8]) {
  asm volatile("" : "+v"(b[0]), "+v"(b[1]), "+v"(b[2]), "+v"(b[3]),
                    "+v"(b[4]), "+v"(b[5]), "+v"(b[6]), "+v"(b[7]));
}

__device__ __forceinline__ void stage8(f4u (&buf)[8],
                                       const float* __restrict__ crow,
                                       int base) {
  #pragma unroll
  for (int k = 0; k < 8; ++k)
    buf[k] = *(const f4u*)&crow[base + 4 * k];
}

__device__ __forceinline__ void stage8_edge(f4u (&buf)[8],
                                            const float* __restrict__ crow,
                                            int base) {
  #pragma unroll
  for (int k = 0; k < 8; ++k)
    #pragma unroll
    for (int j = 0; j < 4; ++j) {
      int col = min(max(base + 4 * k + j, 0), MDIM - 1);
      buf[k][j] = crow[col];
    }
}

// one 32-step phase body; lane l owns row (64s + l); col at step u: cb+u-l.
template <bool FIRST, bool EDGE>
__device__ __forceinline__ void phase32(
    float& o, float& d, float bq, const f4u (&cur)[8],
    int cb, int lane, float* __restrict__ bw) {
  const bool l0 = (lane == 0);
  const bool l63 = (lane == 63);
  float h0, h1, h2, h3;
  #pragma unroll
  for (int u = 0; u < 32; ++u) {
    float t = shr1(o);
    float av;
    if (FIRST) {
      av = l0 ? BIGF : t;
    } else {
      float rv = __builtin_bit_cast(
          float, __builtin_amdgcn_readlane(__builtin_bit_cast(int, bq), u));
      av = l0 ? rv : t;
    }
    float mn, md, mx;
    asm("v_min3_f32 %0, %1, %2, %3" : "=v"(mn) : "v"(d), "v"(av), "v"(o));
    asm("v_med3_f32 %0, %1, %2, %3" : "=v"(md) : "v"(d), "v"(av), "v"(o));
    asm("v_max3_f32 %0, %1, %2, %3" : "=v"(mx) : "v"(d), "v"(av), "v"(o));
    float e = 1.0f + fexp2(mn - md) + fexp2(mn - mx);
    float n = cur[u >> 2][u & 3] + (mn - flog2(e));
    if (EDGE) {
      int c = cb + u - lane;
      bool valid = ((unsigned)c < (unsigned)MDIM);
      n = valid ? n : BIGF;
      if (l63 && valid) bw[c] = n;
    } else {
      if ((u & 3) == 0) h0 = n;
      else if ((u & 3) == 1) h1 = n;
      else if ((u & 3) == 2) h2 = n;
      else {
        h3 = n;
        if (l63) *(f4u*)&bw[cb + u - 66] = (f4u){h0, h1, h2, h3};
      }
    }
    d = av;
    o = n;
  }
}

// one full phase: acquire, stage-next (into nxt), pin cur, body, release.
template <bool FIRST>
__device__ __forceinline__ void do_phase(
    int dq, int s, int lane, f4u (&cur)[8], f4u (&nxt)[8],
    float& o, float& d, float& bqN,
    const float* __restrict__ crow, const float* __restrict__ bp,
    float* __restrict__ bw, int* myf, int* predf, int& pcache) {
  const int p = 4 * s + dq;
  const int cb = dq << 5;
  if (!FIRST && pcache < p) {
    int it = 0;
    do {
      pcache = __hip_atomic_load(predf, __ATOMIC_ACQUIRE,
                                 __HIP_MEMORY_SCOPE_AGENT);
      if (pcache < p) __builtin_amdgcn_s_sleep(1);
    } while (pcache < p && ++it < (1 << 22));
  }
  float bq = bqN;
  // stage next phase's cost window (cols cb+32-lane .. cb+63-lane)
  if (dq >= 1 && dq <= 62)      stage8(nxt, crow, cb + 32 - lane);
  else if (dq != 65)            stage8_edge(nxt, crow, cb + 32 - lane);
  // prefetch next phase's predecessor-bottom chunk (covered: D=4 margin)
  if (!FIRST && dq < 65)
    bqN = aload(&bp[min(cb + 32 + lane, MDIM - 1)]);
  __builtin_amdgcn_sched_barrier(0);
  pin8(cur);   // waitcnt + register-materialize the window staged last phase
  const bool edge = (dq < 2) || (dq > 63);
  if (edge) phase32<FIRST, true>(o, d, bq, cur, cb, lane, bw);
  else      phase32<FIRST, false>(o, d, bq, cur, cb, lane, bw);
  if (lane == 63)
    __hip_atomic_store(myf, p + 1, __ATOMIC_RELEASE,
                       __HIP_MEMORY_SCOPE_AGENT);
}

template <bool FIRST>
__device__ __forceinline__ void run_strip(
    int s, int lane, const float* __restrict__ crow,
    const float* __restrict__ bp, float* __restrict__ bw,
    int* myf, int* predf) {
  f4u bufA[8], bufB[8];
  stage8_edge(bufA, crow, -lane);   // dq=0 window (cols -lane..31-lane)
  float o = BIGF;
  float d = (FIRST && lane == 0) ? 0.0f : BIGF;  // seeds R[0,0]=0 via diag
  float bqN = 0.0f;
  if (!FIRST) bqN = aload(&bp[lane]);            // dq=0 chunk (cols 0..63)
  int pcache = 0;
  #pragma unroll 1
  for (int dq2 = 0; dq2 < 66; dq2 += 2) {
    do_phase<FIRST>(dq2, s, lane, bufA, bufB, o, d, bqN, crow, bp, bw,
                    myf, predf, pcache);
    do_phase<FIRST>(dq2 + 1, s, lane, bufB, bufA, o, d, bqN, crow, bp, bw,
                    myf, predf, pcache);
  }
  if (lane == 63)
    __hip_atomic_store(myf, 1 << 20, __ATOMIC_RELEASE,
                       __HIP_MEMORY_SCOPE_AGENT);
}

__global__ __launch_bounds__(64, 1) void softdtw_dp(
    const float* __restrict__ cost_base, float* __restrict__ bottom,
    int* __restrict__ flags) {
  const int bid = blockIdx.x;
  const int z = bid & 7;          // XCD grouping: matrix z -> XCD z
  if (z >= 3) return;
  const int s = bid >> 3;         // strip 0..31
  const int lane = threadIdx.x;

  const float* cost = cost_base + (size_t)z * MDIM * MDIM;
  const float* crow = cost + (size_t)(s * 64 + lane) * MDIM;
  float* bot_z = bottom + (size_t)z * NSTRIP * MDIM;
  const float* bp = bot_z + (size_t)(s > 0 ? s - 1 : 0) * MDIM;
  float* bw = bot_z + (size_t)s * MDIM;
  int* predf = &flags[z * NSTRIP + (s > 0 ? s - 1 : 0)];
  int* myf = &flags[z * NSTRIP + s];

  if (s == 0) run_strip<true>(s, lane, crow, bp, bw, myf, predf);
  else        run_strip<false>(s, lane, crow, bp, bw, myf, predf);
}

__global__ void dtw_init(int* __restrict__ flags) {
  if (threadIdx.x < 3 * NSTRIP) flags[threadIdx.x] = 0;
}

__global__ void combine(const float* __restrict__ bottom,
                        const float* __restrict__ gamma_p,
                        float* __restrict__ out) {
  float g = fmaxf(fabsf(gamma_p[0]), 1e-4f);
  float glog = 0.69314718056f * g;   // unscale: V = V' * g * ln2
  float b0 = bottom[0 * NSTRIP * MDIM + (NSTRIP - 1) * MDIM + 2047];
  float b1 = bottom[1 * NSTRIP * MDIM + (NSTRIP - 1) * MDIM + 2047];
  float b2 = bottom[2 * NSTRIP * MDIM + (NSTRIP - 1) * MDIM + 2047];
  out[0] = (b0 - 0.5f * (b1 + b2)) * glog;
}

extern "C" void kernel_launch(void* const* d_in, const int* in_sizes, int n_in,
                              void* d_out, int out_size, void* d_ws, size_t ws_size,
                              hipStream_t stream) {
  const float* x = (const float*)d_in[0];
  const float* y = (const float*)d_in[1];
  const float* gamma = (const float*)d_in[2];
  float* out = (float*)d_out;

  char* ws = (char*)d_ws;
  ushort* xb = (ushort*)ws;                                // 4 MB
  ushort* yb = (ushort*)(ws + (size_t)4 * 1024 * 1024);    // 4 MB
  float* cost = (float*)(ws + (size_t)8 * 1024 * 1024);    // 48 MB
  float* bottom = (float*)(ws + (size_t)56 * 1024 * 1024); // 768 KB
  int* flags = (int*)(ws + (size_t)59 * 1024 * 1024);      // 384 B

  normalize_rows<<<(2 * MDIM) / 4, 256, 0, stream>>>(x, y, xb, yb);

  dim3 ggrid(MDIM / 128, MDIM / 128, 3);
  gemm_cost_mfma<<<ggrid, 256, 0, stream>>>(xb, yb, cost, gamma);

  dtw_init<<<1, 128, 0, stream>>>(flags);

  softdtw_dp<<<256, 64, 0, stream>>>(cost, bottom, flags);

  combine<<<1, 1, 0, stream>>>(bottom, gamma, out);
}